// Round 6
// baseline (673.300 us; speedup 1.0000x reference)
//
#include <hip/hip_runtime.h>
#include <hip/hip_bf16.h>
#include <cstdint>

#define HH 128
#define XX 128

typedef __attribute__((ext_vector_type(8))) short short8;
typedef __attribute__((ext_vector_type(4))) short short4_;
typedef __attribute__((ext_vector_type(4))) float float4_;
typedef __attribute__((ext_vector_type(8))) _Float16 half8_;

__device__ __forceinline__ float sigmoidf_(float x) {
  return 1.f / (1.f + __expf(-x));
}
__device__ __forceinline__ float tanhf_(float x) {
  float e = __expf(-2.f * fabsf(x));
  float t = (1.f - e) / (1.f + e);
  return copysignf(t, x);
}

// ================= CSR build =================
__global__ __launch_bounds__(256) void hist_kernel(const int* __restrict__ dst,
                                                   int* __restrict__ cnt, int E) {
  int e = blockIdx.x * 256 + threadIdx.x;
  if (e < E) atomicAdd(&cnt[dst[e]], 1);
}

__global__ __launch_bounds__(256) void scan_block_sum(const int* __restrict__ cnt,
                                                      int* __restrict__ bsum) {
  __shared__ int red[256];
  int b = blockIdx.x, t = threadIdx.x;
  int base = b * 1024 + t * 4;
  int s = cnt[base] + cnt[base + 1] + cnt[base + 2] + cnt[base + 3];
  red[t] = s;
  __syncthreads();
  for (int off = 128; off > 0; off >>= 1) {
    if (t < off) red[t] += red[t + off];
    __syncthreads();
  }
  if (t == 0) bsum[b] = red[0];
}

__global__ __launch_bounds__(256) void scan_top(const int* __restrict__ bsum,
                                                int* __restrict__ boff,
                                                int* __restrict__ row_ptr, int N,
                                                int E) {
  __shared__ int tmp[256];
  int t = threadIdx.x;
  int own = bsum[t];
  tmp[t] = own;
  __syncthreads();
  for (int off = 1; off < 256; off <<= 1) {
    int x = (t >= off) ? tmp[t - off] : 0;
    __syncthreads();
    tmp[t] += x;
    __syncthreads();
  }
  boff[t] = tmp[t] - own;  // exclusive
  if (t == 0) row_ptr[N] = E;
}

__global__ __launch_bounds__(256) void scan_fill(const int* __restrict__ cnt,
                                                 const int* __restrict__ boff,
                                                 int* __restrict__ row_ptr,
                                                 int* __restrict__ row_fill) {
  __shared__ int tsum[256];
  int b = blockIdx.x, t = threadIdx.x;
  int base = b * 1024 + t * 4;
  int v0 = cnt[base], v1 = cnt[base + 1], v2 = cnt[base + 2], v3 = cnt[base + 3];
  int s = v0 + v1 + v2 + v3;
  tsum[t] = s;
  __syncthreads();
  for (int off = 1; off < 256; off <<= 1) {
    int x = (t >= off) ? tsum[t - off] : 0;
    __syncthreads();
    tsum[t] += x;
    __syncthreads();
  }
  int excl = tsum[t] - s + boff[b];
  int p0 = excl, p1 = p0 + v0, p2 = p1 + v1, p3 = p2 + v2;
  row_ptr[base] = p0;
  row_ptr[base + 1] = p1;
  row_ptr[base + 2] = p2;
  row_ptr[base + 3] = p3;
  row_fill[base] = p0;
  row_fill[base + 1] = p1;
  row_fill[base + 2] = p2;
  row_fill[base + 3] = p3;
}

__global__ __launch_bounds__(256) void fill_kernel(const int* __restrict__ src,
                                                   const int* __restrict__ dst,
                                                   int* __restrict__ row_fill,
                                                   int* __restrict__ edge_src,
                                                   int E) {
  int e = blockIdx.x * 256 + threadIdx.x;
  if (e >= E) return;
  int pos = atomicAdd(&row_fill[dst[e]], 1);
  edge_src[pos] = src[e];
}

// ================= weight prep (f16, B-fragment order) =================
// Combined weight Wc[512][256]: rows g*128+col; cols 0..127 from W (te),
// 128..255 from U (hsum for g<3, h for g==3). A col-group cg16's (g,ks)
// fragment is 1024 contiguous bytes: Bh[((g*8+cg16)*8+ks)*512 + c16*32 + kg*8 + j]
__global__ __launch_bounds__(256) void prep_kernel(
    const float* __restrict__ W_iou, const float* __restrict__ U_iou,
    const float* __restrict__ b_iou, const float* __restrict__ U_f_w,
    const float* __restrict__ U_f_b, const float* __restrict__ W_f_w,
    const float* __restrict__ b_f, unsigned short* __restrict__ Bh,
    float* __restrict__ bias) {
  int tid = blockIdx.x * 256 + threadIdx.x;  // 0..16383
  int kg = tid & 3;
  int c16 = (tid >> 2) & 15;
  int ks = (tid >> 6) & 7;
  int w = (tid >> 9) & 7;
  int g = (tid >> 12) & 3;
  int col = w * 16 + c16;
  int kbase = ks * 32 + kg * 8;
#pragma unroll
  for (int j = 0; j < 8; ++j) {
    int k = kbase + j;
    float v;
    if (g < 3) {
      v = (k < 128) ? W_iou[(size_t)(g * 128 + col) * 128 + k]
                    : U_iou[(size_t)(g * 128 + col) * 128 + (k - 128)];
    } else {
      v = (k < 128) ? W_f_w[(size_t)col * 128 + k]
                    : U_f_w[(size_t)col * 128 + (k - 128)];
    }
    Bh[(size_t)tid * 8 + j] = __builtin_bit_cast(unsigned short, (_Float16)v);
  }
  if (tid < 512) {
    int gg = tid >> 7, cc = tid & 127;
    bias[tid] = (gg < 3) ? b_iou[gg * 128 + cc] : (U_f_b[cc] + b_f[cc]);
  }
}

// ================= fused gather + MFMA GEMM + gates =================
// 32-node tile, 256 threads (4 waves), LDS = 32 KB exactly -> 5 blocks/CU.
// LDS halfs layout (all swizzled off = k ^ ((node&7)<<3)):
//   a=0: te   [0,4096)     a=1: hsum [4096,8192)
//   a=2: h    [8192,12288) a=3: c_sum f16 [12288,16384)
// After compute, words [0,8192) reused to assemble h_new/c_new rows.

__device__ __forceinline__ void stage_f16(unsigned short* su, int a, int node,
                                          int k4, float4_ v) {
  unsigned short hq[4];
#pragma unroll
  for (int j = 0; j < 4; ++j)
    hq[j] = __builtin_bit_cast(unsigned short, (_Float16)v[j]);
  int off = k4 ^ ((node & 7) << 3);  // swizzle in half units
  *reinterpret_cast<short4_*>(&su[a * 4096 + node * 128 + off]) =
      *reinterpret_cast<const short4_*>(hq);
}

__device__ __forceinline__ half8_ read_frag(const unsigned short* su, int a,
                                            int node, int kbase, int lane) {
  int k = kbase + ((lane >> 4) << 3);
  int off = k ^ ((node & 7) << 3);
  short8 s = *reinterpret_cast<const short8*>(&su[a * 4096 + node * 128 + off]);
  return __builtin_bit_cast(half8_, s);
}

__device__ __forceinline__ int cw(int row, int col) {  // output-assembly word
  return row * 128 + (col ^ ((row & 7) << 2));
}

__global__ __launch_bounds__(256, 5) void fused_mfma_kernel(
    const float* __restrict__ te, const float* __restrict__ h,
    const float* __restrict__ c, const int* __restrict__ row_ptr,
    const int* __restrict__ edge_src, const unsigned short* __restrict__ Bh,
    const float* __restrict__ bias, float* __restrict__ out_h,
    float* __restrict__ out_c) {
  __shared__ float4_ smem4[2048];  // 32768 bytes
  unsigned short* su = (unsigned short*)smem4;

  const int t = threadIdx.x;
  const int node0 = blockIdx.x * 32;

  // Phase 0: start gather dependency chain EARLY (row_ptr -> edge_src ->
  // first edge's h/c rows into registers) so it overlaps phase A staging.
  const int nl = t >> 3;
  const int sub = t & 7;
  const int e0 = row_ptr[node0 + nl];
  const int e1 = row_ptr[node0 + nl + 1];
  int s0 = (e0 < e1) ? edge_src[e0] : 0;
  float4_ ph[4], pc[4];
  if (e0 < e1) {
    const float* hp = h + (size_t)s0 * HH + sub * 16;
    const float* cp = c + (size_t)s0 * HH + sub * 16;
#pragma unroll
    for (int i = 0; i < 4; ++i) {
      ph[i] = *reinterpret_cast<const float4_*>(hp + i * 4);
      pc[i] = *reinterpret_cast<const float4_*>(cp + i * 4);
    }
  }

  // Phase A: stage te and own-h (streamed, coalesced) as f16
#pragma unroll
  for (int i = 0; i < 4; ++i) {
    int q = t + i * 256;  // 0..1023 float4-chunks
    int node = q >> 5;
    int k4 = (q & 31) * 4;
    float4_ v =
        *reinterpret_cast<const float4_*>(te + (size_t)(node0 + node) * XX + k4);
    stage_f16(su, 0, node, k4, v);
    v = *reinterpret_cast<const float4_*>(h + (size_t)(node0 + node) * HH + k4);
    stage_f16(su, 2, node, k4, v);
  }

  // Phase B: finish gather: 8 threads per node, 16 cols each.
  {
    float hs[16], cs[16];
#pragma unroll
    for (int j = 0; j < 16; ++j) {
      hs[j] = 0.f;
      cs[j] = 0.f;
    }
    if (e0 < e1) {
#pragma unroll
      for (int i = 0; i < 4; ++i)
#pragma unroll
        for (int j = 0; j < 4; ++j) {
          hs[i * 4 + j] += ph[i][j];
          cs[i * 4 + j] += pc[i][j];
        }
    }
    for (int e = e0 + 1; e < e1; ++e) {
      int s = edge_src[e];
      const float* hp = h + (size_t)s * HH + sub * 16;
      const float* cp = c + (size_t)s * HH + sub * 16;
#pragma unroll
      for (int i = 0; i < 4; ++i) {
        float4_ hv = *reinterpret_cast<const float4_*>(hp + i * 4);
        float4_ cv = *reinterpret_cast<const float4_*>(cp + i * 4);
#pragma unroll
        for (int j = 0; j < 4; ++j) {
          hs[i * 4 + j] += hv[j];
          cs[i * 4 + j] += cv[j];
        }
      }
    }
#pragma unroll
    for (int i = 0; i < 4; ++i) {
      float4_ v = {hs[i * 4], hs[i * 4 + 1], hs[i * 4 + 2], hs[i * 4 + 3]};
      stage_f16(su, 1, nl, sub * 16 + i * 4, v);
      float4_ cv = {cs[i * 4], cs[i * 4 + 1], cs[i * 4 + 2], cs[i * 4 + 3]};
      stage_f16(su, 3, nl, sub * 16 + i * 4, cv);
    }
  }
  __syncthreads();

  const int lane = t & 63;
  const int wave = t >> 6;
  const int wc = wave * 32;  // column base (two 16-col groups)
  const int cl = lane & 15;
  const int kq = lane >> 4;

  float4_ acc[4][2][2];  // [gate][m][cg]
#pragma unroll
  for (int g = 0; g < 4; ++g)
#pragma unroll
    for (int cg = 0; cg < 2; ++cg) {
      float b = bias[g * 128 + wc + cg * 16 + cl];
      acc[g][0][cg] = (float4_){b, b, b, b};
      acc[g][1][cg] = (float4_){b, b, b, b};
    }

  for (int ks = 0; ks < 8; ++ks) {
    half8_ bh[4][2];
#pragma unroll
    for (int g = 0; g < 4; ++g)
#pragma unroll
      for (int cg = 0; cg < 2; ++cg) {
        size_t boff =
            (size_t)(((g * 8 + wave * 2 + cg) * 8 + ks) * 512) + cl * 32 + kq * 8;
        bh[g][cg] = __builtin_bit_cast(
            half8_, *reinterpret_cast<const short8*>(&Bh[boff]));
      }
    if (ks < 4) {
      int kbase = ks * 32;
#pragma unroll
      for (int m = 0; m < 2; ++m) {
        half8_ ah = read_frag(su, 0, m * 16 + cl, kbase, lane);
#pragma unroll
        for (int g = 0; g < 4; ++g)
#pragma unroll
          for (int cg = 0; cg < 2; ++cg)
            acc[g][m][cg] = __builtin_amdgcn_mfma_f32_16x16x32_f16(
                ah, bh[g][cg], acc[g][m][cg], 0, 0, 0);
      }
    } else {
      int kbase = (ks - 4) * 32;
#pragma unroll
      for (int m = 0; m < 2; ++m) {
        half8_ ah = read_frag(su, 1, m * 16 + cl, kbase, lane);
        half8_ fh = read_frag(su, 2, m * 16 + cl, kbase, lane);
#pragma unroll
        for (int cg = 0; cg < 2; ++cg) {
#pragma unroll
          for (int g = 0; g < 3; ++g)
            acc[g][m][cg] = __builtin_amdgcn_mfma_f32_16x16x32_f16(
                ah, bh[g][cg], acc[g][m][cg], 0, 0, 0);
          acc[3][m][cg] = __builtin_amdgcn_mfma_f32_16x16x32_f16(
              fh, bh[3][cg], acc[3][m][cg], 0, 0, 0);
        }
      }
    }
  }

  // Epilogue part 1: pull c_sum (f16) into regs before LDS reuse.
  float csv[2][2][4];
#pragma unroll
  for (int m = 0; m < 2; ++m)
#pragma unroll
    for (int cg = 0; cg < 2; ++cg)
#pragma unroll
      for (int r = 0; r < 4; ++r) {
        int row = m * 16 + kq * 4 + r;
        int col = wc + cg * 16 + cl;
        unsigned short hb = su[3 * 4096 + row * 128 + (col ^ ((row & 7) << 3))];
        csv[m][cg][r] = (float)__builtin_bit_cast(_Float16, hb);
      }

  __syncthreads();  // all LDS reads done; safe to reuse for output assembly

  float* oh = (float*)smem4;         // words [0,4096): h_new rows
  float* oc = (float*)smem4 + 4096;  // words [4096,8192): c_new rows

  // Epilogue part 2: gates -> swizzled LDS assembly.
#pragma unroll
  for (int m = 0; m < 2; ++m)
#pragma unroll
    for (int cg = 0; cg < 2; ++cg)
#pragma unroll
      for (int r = 0; r < 4; ++r) {
        int rowl = m * 16 + kq * 4 + r;
        int col = wc + cg * 16 + cl;
        float ig = sigmoidf_(acc[0][m][cg][r]);
        float og = sigmoidf_(acc[1][m][cg][r]);
        float ug = tanhf_(acc[2][m][cg][r]);
        float fg = sigmoidf_(acc[3][m][cg][r]);
        float cn = fmaf(ig, ug, fg * csv[m][cg][r]);
        int wadr = cw(rowl, col);
        oc[wadr] = cn;
        oh[wadr] = og * tanhf_(cn);
      }
  __syncthreads();

  // Stream outputs: fully coalesced float4 rows.
#pragma unroll
  for (int i = 0; i < 4; ++i) {
    int q = t + i * 256;
    int rr = q >> 5;
    int k4 = (q & 31) * 4;
    int wadr = rr * 128 + (k4 ^ ((rr & 7) << 2));
    *reinterpret_cast<float4_*>(out_h + (size_t)(node0 + rr) * HH + k4) =
        *reinterpret_cast<const float4_*>(&oh[wadr]);
    *reinterpret_cast<float4_*>(out_c + (size_t)(node0 + rr) * HH + k4) =
        *reinterpret_cast<const float4_*>(&oc[wadr]);
  }
}

extern "C" void kernel_launch(void* const* d_in, const int* in_sizes, int n_in,
                              void* d_out, int out_size, void* d_ws, size_t ws_size,
                              hipStream_t stream) {
  const float* te = (const float*)d_in[0];
  const float* h = (const float*)d_in[1];
  const float* c = (const float*)d_in[2];
  const int* src = (const int*)d_in[3];
  const int* dst = (const int*)d_in[4];
  const float* W_iou = (const float*)d_in[5];
  const float* U_iou = (const float*)d_in[6];
  const float* b_iou = (const float*)d_in[7];
  const float* U_f_w = (const float*)d_in[8];
  const float* U_f_b = (const float*)d_in[9];
  const float* W_f_w = (const float*)d_in[10];
  const float* b_f = (const float*)d_in[11];

  const int N = in_sizes[1] / HH;
  const int E = in_sizes[3];

  float* out_h = (float*)d_out;
  float* out_c = out_h + (size_t)N * HH;

  // workspace carve-up
  char* ws = (char*)d_ws;
  unsigned short* Bh = (unsigned short*)ws;              // 256 KB
  float* bias = (float*)(Bh + 4 * 8 * 8 * 16 * 4 * 8);   // 2 KB
  int* cnt = (int*)(bias + 512);                         // N ints
  int* row_ptr = cnt + N;                                // N+4 ints
  int* row_fill = row_ptr + N + 4;                       // N ints
  int* edge_src = row_fill + N;                          // E ints
  int* bsum = edge_src + E;                              // 256
  int* boff = bsum + 256;                                // 256

  hipMemsetAsync(cnt, 0, (size_t)N * sizeof(int), stream);

  hist_kernel<<<(E + 255) / 256, 256, 0, stream>>>(dst, cnt, E);
  scan_block_sum<<<N / 1024, 256, 0, stream>>>(cnt, bsum);
  scan_top<<<1, 256, 0, stream>>>(bsum, boff, row_ptr, N, E);
  scan_fill<<<N / 1024, 256, 0, stream>>>(cnt, boff, row_ptr, row_fill);
  fill_kernel<<<(E + 255) / 256, 256, 0, stream>>>(src, dst, row_fill, edge_src, E);

  prep_kernel<<<64, 256, 0, stream>>>(W_iou, U_iou, b_iou, U_f_w, U_f_b, W_f_w,
                                      b_f, Bh, bias);

  fused_mfma_kernel<<<N / 32, 256, 0, stream>>>(te, h, c, row_ptr, edge_src, Bh,
                                                bias, out_h, out_c);
}

// Round 7
// 321.906 us; speedup vs baseline: 2.0916x; 2.0916x over previous
//
#include <hip/hip_runtime.h>
#include <hip/hip_bf16.h>
#include <cstdint>

#define HH 128
#define XX 128

typedef __attribute__((ext_vector_type(8))) short short8;
typedef __attribute__((ext_vector_type(4))) short short4_;
typedef __attribute__((ext_vector_type(4))) float float4_;
typedef __attribute__((ext_vector_type(8))) _Float16 half8_;

__device__ __forceinline__ float sigmoidf_(float x) {
  return 1.f / (1.f + __expf(-x));
}
__device__ __forceinline__ float tanhf_(float x) {
  float e = __expf(-2.f * fabsf(x));
  float t = (1.f - e) / (1.f + e);
  return copysignf(t, x);
}

// ================= CSR build =================
__global__ __launch_bounds__(256) void hist_kernel(const int* __restrict__ dst,
                                                   int* __restrict__ cnt, int E) {
  int e = blockIdx.x * 256 + threadIdx.x;
  if (e < E) atomicAdd(&cnt[dst[e]], 1);
}

__global__ __launch_bounds__(256) void scan_block_sum(const int* __restrict__ cnt,
                                                      int* __restrict__ bsum) {
  __shared__ int red[256];
  int b = blockIdx.x, t = threadIdx.x;
  int base = b * 1024 + t * 4;
  int s = cnt[base] + cnt[base + 1] + cnt[base + 2] + cnt[base + 3];
  red[t] = s;
  __syncthreads();
  for (int off = 128; off > 0; off >>= 1) {
    if (t < off) red[t] += red[t + off];
    __syncthreads();
  }
  if (t == 0) bsum[b] = red[0];
}

__global__ __launch_bounds__(256) void scan_top(const int* __restrict__ bsum,
                                                int* __restrict__ boff,
                                                int* __restrict__ row_ptr, int N,
                                                int E) {
  __shared__ int tmp[256];
  int t = threadIdx.x;
  int own = bsum[t];
  tmp[t] = own;
  __syncthreads();
  for (int off = 1; off < 256; off <<= 1) {
    int x = (t >= off) ? tmp[t - off] : 0;
    __syncthreads();
    tmp[t] += x;
    __syncthreads();
  }
  boff[t] = tmp[t] - own;  // exclusive
  if (t == 0) row_ptr[N] = E;
}

__global__ __launch_bounds__(256) void scan_fill(const int* __restrict__ cnt,
                                                 const int* __restrict__ boff,
                                                 int* __restrict__ row_ptr,
                                                 int* __restrict__ row_fill) {
  __shared__ int tsum[256];
  int b = blockIdx.x, t = threadIdx.x;
  int base = b * 1024 + t * 4;
  int v0 = cnt[base], v1 = cnt[base + 1], v2 = cnt[base + 2], v3 = cnt[base + 3];
  int s = v0 + v1 + v2 + v3;
  tsum[t] = s;
  __syncthreads();
  for (int off = 1; off < 256; off <<= 1) {
    int x = (t >= off) ? tsum[t - off] : 0;
    __syncthreads();
    tsum[t] += x;
    __syncthreads();
  }
  int excl = tsum[t] - s + boff[b];
  int p0 = excl, p1 = p0 + v0, p2 = p1 + v1, p3 = p2 + v2;
  row_ptr[base] = p0;
  row_ptr[base + 1] = p1;
  row_ptr[base + 2] = p2;
  row_ptr[base + 3] = p3;
  row_fill[base] = p0;
  row_fill[base + 1] = p1;
  row_fill[base + 2] = p2;
  row_fill[base + 3] = p3;
}

__global__ __launch_bounds__(256) void fill_kernel(const int* __restrict__ src,
                                                   const int* __restrict__ dst,
                                                   int* __restrict__ row_fill,
                                                   int* __restrict__ edge_src,
                                                   int E) {
  int e = blockIdx.x * 256 + threadIdx.x;
  if (e >= E) return;
  int pos = atomicAdd(&row_fill[dst[e]], 1);
  edge_src[pos] = src[e];
}

// ================= weight prep (f16, B-fragment order) =================
// Combined weight Wc[512][256]: rows g*128+col; cols 0..127 from W (te),
// 128..255 from U (hsum for g<3, h for g==3). Col-group cg16's (g,ks)
// fragment is 1024 contiguous bytes: Bh[((g*8+cg16)*8+ks)*512 + c16*32 + kg*8 + j]
__global__ __launch_bounds__(256) void prep_kernel(
    const float* __restrict__ W_iou, const float* __restrict__ U_iou,
    const float* __restrict__ b_iou, const float* __restrict__ U_f_w,
    const float* __restrict__ U_f_b, const float* __restrict__ W_f_w,
    const float* __restrict__ b_f, unsigned short* __restrict__ Bh,
    float* __restrict__ bias) {
  int tid = blockIdx.x * 256 + threadIdx.x;  // 0..16383
  int kg = tid & 3;
  int c16 = (tid >> 2) & 15;
  int ks = (tid >> 6) & 7;
  int w = (tid >> 9) & 7;
  int g = (tid >> 12) & 3;
  int col = w * 16 + c16;
  int kbase = ks * 32 + kg * 8;
#pragma unroll
  for (int j = 0; j < 8; ++j) {
    int k = kbase + j;
    float v;
    if (g < 3) {
      v = (k < 128) ? W_iou[(size_t)(g * 128 + col) * 128 + k]
                    : U_iou[(size_t)(g * 128 + col) * 128 + (k - 128)];
    } else {
      v = (k < 128) ? W_f_w[(size_t)col * 128 + k]
                    : U_f_w[(size_t)col * 128 + (k - 128)];
    }
    Bh[(size_t)tid * 8 + j] = __builtin_bit_cast(unsigned short, (_Float16)v);
  }
  if (tid < 512) {
    int gg = tid >> 7, cc = tid & 127;
    bias[tid] = (gg < 3) ? b_iou[gg * 128 + cc] : (U_f_b[cc] + b_f[cc]);
  }
}

// ================= fused gather + MFMA GEMM + gates =================
// 32-node tile, 512 threads (8 waves). Wave w owns cols w*16..w*16+15 for ALL
// four gates (epilogue wave-local), m in {0,1}. acc = 32 f32/thread.
// LDS = 32 KB exactly -> 3 blocks/CU at 6 waves/SIMD (VGPR cap 85).
// LDS halfs layout (swizzle off = k ^ ((node&7)<<3)):
//   a=0: te [0,4096)  a=1: hsum [4096,8192)  a=2: h [8192,12288)
//   a=3: c_sum f16 [12288,16384)
// After compute, words [0,8192) reused to assemble h_new/c_new rows.

__device__ __forceinline__ void stage_f16(unsigned short* su, int a, int node,
                                          int k4, float4_ v) {
  unsigned short hq[4];
#pragma unroll
  for (int j = 0; j < 4; ++j)
    hq[j] = __builtin_bit_cast(unsigned short, (_Float16)v[j]);
  int off = k4 ^ ((node & 7) << 3);  // swizzle in half units
  *reinterpret_cast<short4_*>(&su[a * 4096 + node * 128 + off]) =
      *reinterpret_cast<const short4_*>(hq);
}

__device__ __forceinline__ half8_ read_frag(const unsigned short* su, int a,
                                            int node, int kbase, int lane) {
  int k = kbase + ((lane >> 4) << 3);
  int off = k ^ ((node & 7) << 3);
  short8 s = *reinterpret_cast<const short8*>(&su[a * 4096 + node * 128 + off]);
  return __builtin_bit_cast(half8_, s);
}

__device__ __forceinline__ int cw(int row, int col) {  // output-assembly word
  return row * 128 + (col ^ ((row & 7) << 2));
}

__global__ __launch_bounds__(512, 6) void fused_mfma_kernel(
    const float* __restrict__ te, const float* __restrict__ h,
    const float* __restrict__ c, const int* __restrict__ row_ptr,
    const int* __restrict__ edge_src, const unsigned short* __restrict__ Bh,
    const float* __restrict__ bias, float* __restrict__ out_h,
    float* __restrict__ out_c) {
  __shared__ float4_ smem4[2048];  // 32768 bytes
  unsigned short* su = (unsigned short*)smem4;

  const int t = threadIdx.x;
  const int node0 = blockIdx.x * 32;

  // Phase 0: start gather dependency chain EARLY. 16 threads per node,
  // each owns 8 cols [sub*8, sub*8+8).
  const int nl = t >> 4;
  const int sub = t & 15;
  const int e0 = row_ptr[node0 + nl];
  const int e1 = row_ptr[node0 + nl + 1];
  int s0 = (e0 < e1) ? edge_src[e0] : 0;
  float4_ ph[2], pc[2];
  if (e0 < e1) {
    const float* hp = h + (size_t)s0 * HH + sub * 8;
    const float* cp = c + (size_t)s0 * HH + sub * 8;
#pragma unroll
    for (int i = 0; i < 2; ++i) {
      ph[i] = *reinterpret_cast<const float4_*>(hp + i * 4);
      pc[i] = *reinterpret_cast<const float4_*>(cp + i * 4);
    }
  }

  // Phase A: stage te and own-h (streamed, coalesced) as f16
#pragma unroll
  for (int i = 0; i < 2; ++i) {
    int q = t + i * 512;  // 0..1023 float4-chunks (32 rows x 32 chunks)
    int node = q >> 5;
    int k4 = (q & 31) * 4;
    float4_ v =
        *reinterpret_cast<const float4_*>(te + (size_t)(node0 + node) * XX + k4);
    stage_f16(su, 0, node, k4, v);
    v = *reinterpret_cast<const float4_*>(h + (size_t)(node0 + node) * HH + k4);
    stage_f16(su, 2, node, k4, v);
  }

  // Phase B: finish gather: 16 threads per node, 8 cols each.
  {
    float hs[8], cs[8];
#pragma unroll
    for (int j = 0; j < 8; ++j) {
      hs[j] = 0.f;
      cs[j] = 0.f;
    }
    if (e0 < e1) {
#pragma unroll
      for (int i = 0; i < 2; ++i)
#pragma unroll
        for (int j = 0; j < 4; ++j) {
          hs[i * 4 + j] += ph[i][j];
          cs[i * 4 + j] += pc[i][j];
        }
    }
    for (int e = e0 + 1; e < e1; ++e) {
      int s = edge_src[e];
      const float* hp = h + (size_t)s * HH + sub * 8;
      const float* cp = c + (size_t)s * HH + sub * 8;
#pragma unroll
      for (int i = 0; i < 2; ++i) {
        float4_ hv = *reinterpret_cast<const float4_*>(hp + i * 4);
        float4_ cv = *reinterpret_cast<const float4_*>(cp + i * 4);
#pragma unroll
        for (int j = 0; j < 4; ++j) {
          hs[i * 4 + j] += hv[j];
          cs[i * 4 + j] += cv[j];
        }
      }
    }
#pragma unroll
    for (int i = 0; i < 2; ++i) {
      float4_ v = {hs[i * 4], hs[i * 4 + 1], hs[i * 4 + 2], hs[i * 4 + 3]};
      stage_f16(su, 1, nl, sub * 8 + i * 4, v);
      float4_ cv = {cs[i * 4], cs[i * 4 + 1], cs[i * 4 + 2], cs[i * 4 + 3]};
      stage_f16(su, 3, nl, sub * 8 + i * 4, cv);
    }
  }
  __syncthreads();

  const int lane = t & 63;
  const int wave = t >> 6;
  const int wc = wave * 16;  // column base (one 16-col group, all 4 gates)
  const int cl = lane & 15;
  const int kq = lane >> 4;

  float4_ acc[4][2];  // [gate][m], bias added at epilogue
#pragma unroll
  for (int g = 0; g < 4; ++g)
#pragma unroll
    for (int m = 0; m < 2; ++m) acc[g][m] = (float4_){0.f, 0.f, 0.f, 0.f};

  for (int ks = 0; ks < 8; ++ks) {
    half8_ bh[4];
#pragma unroll
    for (int g = 0; g < 4; ++g) {
      size_t boff = (size_t)(((g * 8 + wave) * 8 + ks) * 512) + cl * 32 + kq * 8;
      bh[g] = __builtin_bit_cast(half8_,
                                 *reinterpret_cast<const short8*>(&Bh[boff]));
    }
    if (ks < 4) {
      int kbase = ks * 32;
#pragma unroll
      for (int m = 0; m < 2; ++m) {
        half8_ ah = read_frag(su, 0, m * 16 + cl, kbase, lane);
#pragma unroll
        for (int g = 0; g < 4; ++g)
          acc[g][m] = __builtin_amdgcn_mfma_f32_16x16x32_f16(ah, bh[g],
                                                             acc[g][m], 0, 0, 0);
      }
    } else {
      int kbase = (ks - 4) * 32;
#pragma unroll
      for (int m = 0; m < 2; ++m) {
        half8_ ah = read_frag(su, 1, m * 16 + cl, kbase, lane);
        half8_ fh = read_frag(su, 2, m * 16 + cl, kbase, lane);
#pragma unroll
        for (int g = 0; g < 3; ++g)
          acc[g][m] = __builtin_amdgcn_mfma_f32_16x16x32_f16(ah, bh[g],
                                                             acc[g][m], 0, 0, 0);
        acc[3][m] = __builtin_amdgcn_mfma_f32_16x16x32_f16(fh, bh[3],
                                                           acc[3][m], 0, 0, 0);
      }
    }
  }

  // Epilogue part 1: pull c_sum (f16) + bias into regs before LDS reuse.
  const int col = wc + cl;
  float bi = bias[0 * 128 + col];
  float bo = bias[1 * 128 + col];
  float bu = bias[2 * 128 + col];
  float bf = bias[3 * 128 + col];
  float csv[2][4];
#pragma unroll
  for (int m = 0; m < 2; ++m)
#pragma unroll
    for (int r = 0; r < 4; ++r) {
      int row = m * 16 + kq * 4 + r;
      unsigned short hb = su[3 * 4096 + row * 128 + (col ^ ((row & 7) << 3))];
      csv[m][r] = (float)__builtin_bit_cast(_Float16, hb);
    }

  __syncthreads();  // all LDS reads done; safe to reuse for output assembly

  float* oh = (float*)smem4;         // words [0,4096): h_new rows
  float* oc = (float*)smem4 + 4096;  // words [4096,8192): c_new rows

  // Epilogue part 2: gates -> swizzled LDS assembly.
#pragma unroll
  for (int m = 0; m < 2; ++m)
#pragma unroll
    for (int r = 0; r < 4; ++r) {
      int rowl = m * 16 + kq * 4 + r;
      float ig = sigmoidf_(acc[0][m][r] + bi);
      float og = sigmoidf_(acc[1][m][r] + bo);
      float ug = tanhf_(acc[2][m][r] + bu);
      float fg = sigmoidf_(acc[3][m][r] + bf);
      float cn = fmaf(ig, ug, fg * csv[m][r]);
      int wadr = cw(rowl, col);
      oc[wadr] = cn;
      oh[wadr] = og * tanhf_(cn);
    }
  __syncthreads();

  // Stream outputs: fully coalesced float4 rows.
#pragma unroll
  for (int i = 0; i < 2; ++i) {
    int q = t + i * 512;
    int rr = q >> 5;
    int k4 = (q & 31) * 4;
    int wadr = rr * 128 + (k4 ^ ((rr & 7) << 2));
    *reinterpret_cast<float4_*>(out_h + (size_t)(node0 + rr) * HH + k4) =
        *reinterpret_cast<const float4_*>(&oh[wadr]);
    *reinterpret_cast<float4_*>(out_c + (size_t)(node0 + rr) * HH + k4) =
        *reinterpret_cast<const float4_*>(&oc[wadr]);
  }
}

extern "C" void kernel_launch(void* const* d_in, const int* in_sizes, int n_in,
                              void* d_out, int out_size, void* d_ws, size_t ws_size,
                              hipStream_t stream) {
  const float* te = (const float*)d_in[0];
  const float* h = (const float*)d_in[1];
  const float* c = (const float*)d_in[2];
  const int* src = (const int*)d_in[3];
  const int* dst = (const int*)d_in[4];
  const float* W_iou = (const float*)d_in[5];
  const float* U_iou = (const float*)d_in[6];
  const float* b_iou = (const float*)d_in[7];
  const float* U_f_w = (const float*)d_in[8];
  const float* U_f_b = (const float*)d_in[9];
  const float* W_f_w = (const float*)d_in[10];
  const float* b_f = (const float*)d_in[11];

  const int N = in_sizes[1] / HH;
  const int E = in_sizes[3];

  float* out_h = (float*)d_out;
  float* out_c = out_h + (size_t)N * HH;

  // workspace carve-up
  char* ws = (char*)d_ws;
  unsigned short* Bh = (unsigned short*)ws;              // 256 KB
  float* bias = (float*)(Bh + 4 * 8 * 8 * 16 * 4 * 8);   // 2 KB
  int* cnt = (int*)(bias + 512);                         // N ints
  int* row_ptr = cnt + N;                                // N+4 ints
  int* row_fill = row_ptr + N + 4;                       // N ints
  int* edge_src = row_fill + N;                          // E ints
  int* bsum = edge_src + E;                              // 256
  int* boff = bsum + 256;                                // 256

  hipMemsetAsync(cnt, 0, (size_t)N * sizeof(int), stream);

  hist_kernel<<<(E + 255) / 256, 256, 0, stream>>>(dst, cnt, E);
  scan_block_sum<<<N / 1024, 256, 0, stream>>>(cnt, bsum);
  scan_top<<<1, 256, 0, stream>>>(bsum, boff, row_ptr, N, E);
  scan_fill<<<N / 1024, 256, 0, stream>>>(cnt, boff, row_ptr, row_fill);
  fill_kernel<<<(E + 255) / 256, 256, 0, stream>>>(src, dst, row_fill, edge_src, E);

  prep_kernel<<<64, 256, 0, stream>>>(W_iou, U_iou, b_iou, U_f_w, U_f_b, W_f_w,
                                      b_f, Bh, bias);

  fused_mfma_kernel<<<N / 32, 512, 0, stream>>>(te, h, c, row_ptr, edge_src, Bh,
                                                bias, out_h, out_c);
}